// Round 2
// baseline (255.050 us; speedup 1.0000x reference)
//
#include <hip/hip_runtime.h>

#define NNODES 100000
#define NEDGES 1600000
#define BSHIFT 7
#define NB 782            // buckets of 128 nodes: bucket = dst >> 7
#define CAP 2560          // padded per-bucket capacity (mean 2048, +11 sigma)
#define EBLOCKS 391       // edge-scatter blocks (4096 edges each)
#define GEMM_BLOCKS 1563  // (NNODES + 63) / 64

typedef _Float16 f16;
typedef _Float16 v4h __attribute__((ext_vector_type(4)));
typedef _Float16 v8h __attribute__((ext_vector_type(8)));
typedef float v4f __attribute__((ext_vector_type(4)));

// ---------------------------------------------------------------------------
// Init: bucket cursors (bcur[b] = b*CAP) + weight transpose/convert to f16.
// ---------------------------------------------------------------------------
__global__ __launch_bounds__(256) void init_k(int* __restrict__ bcur,
                                              const float* __restrict__ W1,
                                              f16* __restrict__ W1t,
                                              const float* __restrict__ W2,
                                              f16* __restrict__ W2t) {
    int t = blockIdx.x * 256 + threadIdx.x;
    if (t < NB) bcur[t] = t * CAP;
    int u = t - 1024;
    if (u >= 0) {
        if (u < 128 * 128) {
            int k = u >> 7, n = u & 127;
            W1t[n * 128 + k] = (f16)W1[k * 128 + n];
        } else if (u < 128 * 128 + 128 * 64) {
            int v = u - 128 * 128;
            int k = v >> 6, n = v & 63;
            W2t[n * 128 + k] = (f16)W2[k * 64 + n];
        }
    }
}

// ---------------------------------------------------------------------------
// Fused: edge scatter into bucket-padded ebuf (blocks 0..EBLOCKS-1) +
// layer-1 MFMA GEMM with inline fp32->f16 A conversion (remaining blocks).
// ebuf entry packed 4B: src | (dst&127)<<24  (src < 2^17).
// ---------------------------------------------------------------------------
__global__ __launch_bounds__(256) void scatter_gemm1(
    const int* __restrict__ src, const int* __restrict__ dst,
    int* __restrict__ bcur, int* __restrict__ ebuf,
    const float* __restrict__ feat, const f16* __restrict__ W1t,
    f16* __restrict__ z1) {
    constexpr int PITCH = 136;
    __shared__ __align__(16) char smem[128 * PITCH * 2];  // 34816 B
    int tid = threadIdx.x;

    if (blockIdx.x < EBLOCKS) {
        int* h = (int*)smem;
        int* base_s = ((int*)smem) + 1024;
        for (int i = tid; i < NB; i += 256) h[i] = 0;
        __syncthreads();
        int base = blockIdx.x * 4096;
        int d[16], sv[16];
        for (int k = 0; k < 16; k++) {
            int e = base + k * 256 + tid;
            if (e < NEDGES) {
                d[k] = dst[e];
                sv[k] = src[e];
                atomicAdd(&h[d[k] >> BSHIFT], 1);
            } else {
                d[k] = -1;
            }
        }
        __syncthreads();
        for (int i = tid; i < NB; i += 256) {
            int c = h[i];
            if (c) base_s[i] = atomicAdd(&bcur[i], c);
            h[i] = 0;
        }
        __syncthreads();
        for (int k = 0; k < 16; k++) {
            if (d[k] >= 0) {
                int b = d[k] >> BSHIFT;
                int slot = atomicAdd(&h[b], 1);
                ebuf[base_s[b] + slot] = sv[k] | ((d[k] & 127) << 24);
            }
        }
        return;
    }

    // ---- GEMM-1 branch: z1 = f16(feat) @ W1t^T ----
    f16* wlds = (f16*)smem;
    for (int c = tid; c < 128 * 16; c += 256) {
        int n = c >> 4;
        int kc = c & 15;
        *(v8h*)&wlds[n * PITCH + kc * 8] = *(const v8h*)&W1t[n * 128 + kc * 8];
    }
    __syncthreads();

    int wave = tid >> 6, lane = tid & 63, quad = lane >> 4, l16 = lane & 15;
    int m0 = (blockIdx.x - EBLOCKS) * 64 + wave * 16;
    if (m0 >= NNODES) return;  // NNODES % 16 == 0

    v8h a[4];
    const float* arow = feat + (long)(m0 + l16) * 128 + quad * 8;
#pragma unroll
    for (int kb = 0; kb < 4; kb++) {
        float4 f0 = *(const float4*)(arow + kb * 32);
        float4 f1 = *(const float4*)(arow + kb * 32 + 4);
        v8h t = {(f16)f0.x, (f16)f0.y, (f16)f0.z, (f16)f0.w,
                 (f16)f1.x, (f16)f1.y, (f16)f1.z, (f16)f1.w};
        a[kb] = t;
    }

#pragma unroll
    for (int nt = 0; nt < 8; nt++) {
        v4f acc = {0.f, 0.f, 0.f, 0.f};
        const f16* brow = &wlds[(nt * 16 + l16) * PITCH + quad * 8];
#pragma unroll
        for (int kb = 0; kb < 4; kb++) {
            v8h b = *(const v8h*)(brow + kb * 32);
            acc = __builtin_amdgcn_mfma_f32_16x16x32_f16(a[kb], b, acc, 0, 0, 0);
        }
        int n = nt * 16 + l16;
#pragma unroll
        for (int r = 0; r < 4; r++)
            z1[(long)(m0 + quad * 4 + r) * 128 + n] = (f16)acc[r];
    }
}

// ---------------------------------------------------------------------------
// Per-bucket CSR fill (padded layout): count 128 nodes in LDS, scan, write
// begs/ends, place edges via LDS cursors. All writes in a ~10KB window.
// ---------------------------------------------------------------------------
__global__ __launch_bounds__(256) void fill_bucket(const int* __restrict__ ebuf,
                                                   const int* __restrict__ bcur,
                                                   int* __restrict__ begs,
                                                   int* __restrict__ ends,
                                                   int* __restrict__ csr) {
    __shared__ int lc[128];
    __shared__ int ls[256];
    int b = blockIdx.x;
    int tid = threadIdx.x;
    if (tid < 128) lc[tid] = 0;
    __syncthreads();
    int ebeg = b * CAP;
    int eend = bcur[b];  // = b*CAP + bucket count
    for (int e = ebeg + tid; e < eend; e += 256)
        atomicAdd(&lc[((unsigned)ebuf[e]) >> 24], 1);
    __syncthreads();
    int cnt = (tid < 128) ? lc[tid] : 0;
    ls[tid] = cnt;
    __syncthreads();
    for (int off = 1; off < 256; off <<= 1) {
        int t = (tid >= off) ? ls[tid - off] : 0;
        __syncthreads();
        ls[tid] += t;
        __syncthreads();
    }
    int excl = ls[tid] - cnt;
    int node = (b << BSHIFT) + tid;
    if (tid < 128 && node < NNODES) {
        begs[node] = ebeg + excl;
        ends[node] = ebeg + excl + cnt;
    }
    if (tid < 128) { ls[tid] = excl; lc[tid] = 0; }
    __syncthreads();
    for (int e = ebeg + tid; e < eend; e += 256) {
        int p = ebuf[e];
        int dloc = ((unsigned)p) >> 24;
        int slot = atomicAdd(&lc[dloc], 1);
        csr[ebeg + ls[dloc] + slot] = p & 0xFFFFFF;
    }
}

// ---------------------------------------------------------------------------
// Fused layer-1 gather + layer-2 projection. 1024-thread blocks = 16 waves =
// 16 nodes. Wave = 4x 16-lane subgroups; each subgroup reads a full 256B z1
// row per v8h load, one predicated 32-edge shot per iteration. An asm
// keep-alive after the 8 loads forces ALL EIGHT to be issued before the
// first wait (VGPR_Count=32 last round proved the compiler was chunking to
// ~2-deep MLP). 32-bit byte-offset addressing (idx<<8 | c<<4) replaces the
// 64-bit mul chain. Numerics identical to round 1.
// ---------------------------------------------------------------------------
__global__ __launch_bounds__(1024, 8) void gather128_gemm2(
    const f16* __restrict__ z,        // z1, 256 B rows
    const int* __restrict__ begs, const int* __restrict__ ends,
    const int* __restrict__ csr,
    const float* __restrict__ b1,     // [128]
    const f16* __restrict__ W2t,      // [64,128]
    f16* __restrict__ z2)             // [NNODES,64]
{
    constexpr int PITCH = 136;
    __shared__ f16 w2lds[64 * PITCH];   // 17408 B
    __shared__ f16 atile[16 * PITCH];   //  4352 B
    int tid = threadIdx.x;

    // stage W2t (1024 threads, exactly 64*16 8-half chunks)
    {
        int n = tid >> 4, kc = tid & 15;
        *(v8h*)&w2lds[n * PITCH + kc * 8] = *(const v8h*)&W2t[n * 128 + kc * 8];
    }

    int wavei = tid >> 6;  // local node 0..15
    int lane = tid & 63;
    int sub = lane >> 4;   // edge subgroup 0..3
    int c = lane & 15;     // channel block: halves c*8 .. c*8+7
    int node = blockIdx.x * 16 + wavei;  // 6250*16 == NNODES exactly

    int beg = begs[node];
    int end = ends[node];

    const char* zb = (const char*)z;
    unsigned coff = (unsigned)c << 4;   // byte offset of this lane's 16B chunk

    // self row issued early so its latency overlaps the edge loop
    v8h sv = {0, 0, 0, 0, 0, 0, 0, 0};
    if (sub == 0) sv = *(const v8h*)(zb + ((unsigned)node << 8) + coff);

    float af[8];
#pragma unroll
    for (int j = 0; j < 8; j++) af[j] = 0.f;

    for (int e = beg; e < end; e += 32) {
        v8h u0 = {0,0,0,0,0,0,0,0}, u1 = {0,0,0,0,0,0,0,0};
        v8h u2 = {0,0,0,0,0,0,0,0}, u3 = {0,0,0,0,0,0,0,0};
        v8h u4 = {0,0,0,0,0,0,0,0}, u5 = {0,0,0,0,0,0,0,0};
        v8h u6 = {0,0,0,0,0,0,0,0}, u7 = {0,0,0,0,0,0,0,0};
        int i;
        i = e + sub;      if (i < end) u0 = *(const v8h*)(zb + (((unsigned)csr[i]) << 8) + coff);
        i = e + 4 + sub;  if (i < end) u1 = *(const v8h*)(zb + (((unsigned)csr[i]) << 8) + coff);
        i = e + 8 + sub;  if (i < end) u2 = *(const v8h*)(zb + (((unsigned)csr[i]) << 8) + coff);
        i = e + 12 + sub; if (i < end) u3 = *(const v8h*)(zb + (((unsigned)csr[i]) << 8) + coff);
        i = e + 16 + sub; if (i < end) u4 = *(const v8h*)(zb + (((unsigned)csr[i]) << 8) + coff);
        i = e + 20 + sub; if (i < end) u5 = *(const v8h*)(zb + (((unsigned)csr[i]) << 8) + coff);
        i = e + 24 + sub; if (i < end) u6 = *(const v8h*)(zb + (((unsigned)csr[i]) << 8) + coff);
        i = e + 28 + sub; if (i < end) u7 = *(const v8h*)(zb + (((unsigned)csr[i]) << 8) + coff);
        // Force all 8 loads to be in flight before the first consumption:
        // one wait for the batch instead of compiler wait-per-pair chunking.
        asm volatile("" : "+v"(u0), "+v"(u1), "+v"(u2), "+v"(u3),
                          "+v"(u4), "+v"(u5), "+v"(u6), "+v"(u7));
        v8h s01 = u0 + u1, s23 = u2 + u3, s45 = u4 + u5, s67 = u6 + u7;
        v8h s03 = s01 + s23, s47 = s45 + s67;
        v8h s = s03 + s47;   // 8-wide f16 tree (same depth as before)
#pragma unroll
        for (int j = 0; j < 8; j++) af[j] += (float)s[j];
    }
#pragma unroll
    for (int j = 0; j < 8; j++) af[j] += (float)sv[j];

    // reduce across the 4 edge subgroups (fp32)
#pragma unroll
    for (int j = 0; j < 8; j++) {
        af[j] += __shfl_xor(af[j], 16);
        af[j] += __shfl_xor(af[j], 32);
    }

    if (sub == 0) {
        float inv = 1.0f / (float)(end - beg + 1);
        float4 bb0 = ((const float4*)b1)[c * 2];
        float4 bb1 = ((const float4*)b1)[c * 2 + 1];
        v8h o = {(f16)fmaxf(af[0] * inv + bb0.x, 0.f),
                 (f16)fmaxf(af[1] * inv + bb0.y, 0.f),
                 (f16)fmaxf(af[2] * inv + bb0.z, 0.f),
                 (f16)fmaxf(af[3] * inv + bb0.w, 0.f),
                 (f16)fmaxf(af[4] * inv + bb1.x, 0.f),
                 (f16)fmaxf(af[5] * inv + bb1.y, 0.f),
                 (f16)fmaxf(af[6] * inv + bb1.z, 0.f),
                 (f16)fmaxf(af[7] * inv + bb1.w, 0.f)};
        *(v8h*)&atile[wavei * PITCH + c * 8] = o;
    }
    __syncthreads();

    // ---- epilogue: z2[16 rows] = atile @ W2t^T, waves 0..3 (one n-tile each)
    if (wavei < 4) {
        int quad = lane >> 4, l16 = lane & 15;
        const f16* arow = &atile[l16 * PITCH + quad * 8];
        const f16* brow = &w2lds[(wavei * 16 + l16) * PITCH + quad * 8];
        v4f acc = {0.f, 0.f, 0.f, 0.f};
#pragma unroll
        for (int kb = 0; kb < 4; kb++) {
            v8h av = *(const v8h*)(arow + kb * 32);
            v8h bv = *(const v8h*)(brow + kb * 32);
            acc = __builtin_amdgcn_mfma_f32_16x16x32_f16(av, bv, acc, 0, 0, 0);
        }
        int n = wavei * 16 + l16;
        int m0 = blockIdx.x * 16;
#pragma unroll
        for (int r = 0; r < 4; r++)
            z2[(long)(m0 + quad * 4 + r) * 64 + n] = (f16)acc[r];
    }
}

// ---------------------------------------------------------------------------
// Layer-2 gather+normalize over 64-wide f16 rows, fp32 out:
//   out[n] = (Σ z2[src] + z2[n]) / (deg+1) + b2
// Wave = 8x 8-lane subgroups; 128 B rows, predicated 64-edge shot; same asm
// keep-alive to force 8-deep MLP; 32-bit byte offsets (idx<<7 | c<<4).
// ---------------------------------------------------------------------------
__global__ __launch_bounds__(256, 8) void gather64(
    const f16* __restrict__ z, const int* __restrict__ begs,
    const int* __restrict__ ends, const int* __restrict__ csr,
    const float* __restrict__ bias, float4* __restrict__ out) {
    int node = (int)(((long)blockIdx.x * blockDim.x + threadIdx.x) >> 6);
    if (node >= NNODES) return;
    int lane = threadIdx.x & 63;
    int sub = lane >> 3;  // edge subgroup 0..7
    int c = lane & 7;     // channel block: halves c*8 .. c*8+7

    int beg = begs[node];
    int end = ends[node];

    const char* zb = (const char*)z;
    unsigned coff = (unsigned)c << 4;

    v8h sv = {0, 0, 0, 0, 0, 0, 0, 0};
    if (sub == 0) sv = *(const v8h*)(zb + ((unsigned)node << 7) + coff);

    float af[8];
#pragma unroll
    for (int j = 0; j < 8; j++) af[j] = 0.f;

    for (int e = beg; e < end; e += 64) {
        v8h u0 = {0,0,0,0,0,0,0,0}, u1 = {0,0,0,0,0,0,0,0};
        v8h u2 = {0,0,0,0,0,0,0,0}, u3 = {0,0,0,0,0,0,0,0};
        v8h u4 = {0,0,0,0,0,0,0,0}, u5 = {0,0,0,0,0,0,0,0};
        v8h u6 = {0,0,0,0,0,0,0,0}, u7 = {0,0,0,0,0,0,0,0};
        int i;
        i = e + sub;      if (i < end) u0 = *(const v8h*)(zb + (((unsigned)csr[i]) << 7) + coff);
        i = e + 8 + sub;  if (i < end) u1 = *(const v8h*)(zb + (((unsigned)csr[i]) << 7) + coff);
        i = e + 16 + sub; if (i < end) u2 = *(const v8h*)(zb + (((unsigned)csr[i]) << 7) + coff);
        i = e + 24 + sub; if (i < end) u3 = *(const v8h*)(zb + (((unsigned)csr[i]) << 7) + coff);
        i = e + 32 + sub; if (i < end) u4 = *(const v8h*)(zb + (((unsigned)csr[i]) << 7) + coff);
        i = e + 40 + sub; if (i < end) u5 = *(const v8h*)(zb + (((unsigned)csr[i]) << 7) + coff);
        i = e + 48 + sub; if (i < end) u6 = *(const v8h*)(zb + (((unsigned)csr[i]) << 7) + coff);
        i = e + 56 + sub; if (i < end) u7 = *(const v8h*)(zb + (((unsigned)csr[i]) << 7) + coff);
        asm volatile("" : "+v"(u0), "+v"(u1), "+v"(u2), "+v"(u3),
                          "+v"(u4), "+v"(u5), "+v"(u6), "+v"(u7));
        v8h s01 = u0 + u1, s23 = u2 + u3, s45 = u4 + u5, s67 = u6 + u7;
        v8h s03 = s01 + s23, s47 = s45 + s67;
        v8h s = s03 + s47;
#pragma unroll
        for (int j = 0; j < 8; j++) af[j] += (float)s[j];
    }
#pragma unroll
    for (int j = 0; j < 8; j++) af[j] += (float)sv[j];

    // reduce across the 8 edge subgroups (fp32)
#pragma unroll
    for (int j = 0; j < 8; j++) {
        af[j] += __shfl_xor(af[j], 8);
        af[j] += __shfl_xor(af[j], 16);
        af[j] += __shfl_xor(af[j], 32);
    }

    if (sub == 0) {
        float inv = 1.0f / (float)(end - beg + 1);
        float4 b0 = ((const float4*)bias)[c * 2];
        float4 b1v = ((const float4*)bias)[c * 2 + 1];
        out[(long)node * 16 + c * 2] =
            make_float4(af[0] * inv + b0.x, af[1] * inv + b0.y,
                        af[2] * inv + b0.z, af[3] * inv + b0.w);
        out[(long)node * 16 + c * 2 + 1] =
            make_float4(af[4] * inv + b1v.x, af[5] * inv + b1v.y,
                        af[6] * inv + b1v.z, af[7] * inv + b1v.w);
    }
}

extern "C" void kernel_launch(void* const* d_in, const int* in_sizes, int n_in,
                              void* d_out, int out_size, void* d_ws, size_t ws_size,
                              hipStream_t stream) {
    const float* feat = (const float*)d_in[0];
    const float* W1   = (const float*)d_in[1];
    const float* b1   = (const float*)d_in[2];
    const float* W2   = (const float*)d_in[3];
    const float* b2   = (const float*)d_in[4];
    const int*   src  = (const int*)d_in[5];
    const int*   dst  = (const int*)d_in[6];
    float* out = (float*)d_out;

    // Workspace layout:
    //   bcur i32[782]       @ 0x0000000
    //   begs i32[100000]    @ 0x0001000  (400000 B)
    //   ends i32[100000]    @ 0x0063000  (400000 B)
    //   csr  i32[NB*CAP=2001920] @ 0x00C5000  (8.0 MB, bucket-padded)
    //   ebuf i32[NB*CAP]    @ 0x0870000  (8.0 MB, bucket-padded)
    //   z1   f16[12.8M]     @ 0x1100000  (25.6 MB)
    //   z2   f16[6.4M]      @ 0x2A00000  (12.8 MB)
    //   W1t  f16[16384]     @ 0x3700000
    //   W2t  f16[8192]      @ 0x3710000
    char* ws = (char*)d_ws;
    int* bcur = (int*)(ws + 0x0000000);
    int* begs = (int*)(ws + 0x0001000);
    int* ends = (int*)(ws + 0x0063000);
    int* csr  = (int*)(ws + 0x00C5000);
    int* ebuf = (int*)(ws + 0x0870000);
    f16* z1   = (f16*)(ws + 0x1100000);
    f16* z2   = (f16*)(ws + 0x2A00000);
    f16* W1t  = (f16*)(ws + 0x3700000);
    f16* W2t  = (f16*)(ws + 0x3710000);

    // 1. init cursors + weight prep (no memsets needed anywhere)
    init_k<<<100, 256, 0, stream>>>(bcur, W1, W1t, W2, W2t);

    // 2. edge scatter into padded buckets + layer-1 GEMM (fused)
    scatter_gemm1<<<EBLOCKS + GEMM_BLOCKS, 256, 0, stream>>>(src, dst, bcur, ebuf,
                                                             feat, W1t, z1);

    // 3. per-bucket CSR fill + per-node beg/end
    fill_bucket<<<NB, 256, 0, stream>>>(ebuf, bcur, begs, ends, csr);

    // 4. layer-1 gather (+bias+relu) fused with layer-2 projection
    gather128_gemm2<<<NNODES / 16, 1024, 0, stream>>>(z1, begs, ends,
                                                      csr, b1, W2t, z2);

    // 5. layer-2 gather (+bias) -> output
    gather64<<<(NNODES * 64 + 255) / 256, 256, 0, stream>>>(z2, begs,
                                                            ends, csr, b2,
                                                            (float4*)out);
}

// Round 3
// 247.857 us; speedup vs baseline: 1.0290x; 1.0290x over previous
//
#include <hip/hip_runtime.h>

#define NNODES 100000
#define NEDGES 1600000
#define BSHIFT 7
#define NB 782            // buckets of 128 nodes: bucket = dst >> 7
#define CAP 2560          // padded per-bucket capacity (mean 2048, +11 sigma)
#define EBLOCKS 391       // edge-scatter blocks (4096 edges each)
#define GEMM_BLOCKS 1563  // (NNODES + 63) / 64

typedef _Float16 f16;
typedef _Float16 v4h __attribute__((ext_vector_type(4)));
typedef _Float16 v8h __attribute__((ext_vector_type(8)));
typedef float v4f __attribute__((ext_vector_type(4)));

// ---------------------------------------------------------------------------
// Init: bucket cursors (bcur[b] = b*CAP) + weight transpose/convert to f16.
// ---------------------------------------------------------------------------
__global__ __launch_bounds__(256) void init_k(int* __restrict__ bcur,
                                              const float* __restrict__ W1,
                                              f16* __restrict__ W1t,
                                              const float* __restrict__ W2,
                                              f16* __restrict__ W2t) {
    int t = blockIdx.x * 256 + threadIdx.x;
    if (t < NB) bcur[t] = t * CAP;
    int u = t - 1024;
    if (u >= 0) {
        if (u < 128 * 128) {
            int k = u >> 7, n = u & 127;
            W1t[n * 128 + k] = (f16)W1[k * 128 + n];
        } else if (u < 128 * 128 + 128 * 64) {
            int v = u - 128 * 128;
            int k = v >> 6, n = v & 63;
            W2t[n * 128 + k] = (f16)W2[k * 64 + n];
        }
    }
}

// ---------------------------------------------------------------------------
// Fused: edge scatter into bucket-padded ebuf (blocks 0..EBLOCKS-1) +
// layer-1 MFMA GEMM with inline fp32->f16 A conversion (remaining blocks).
// ebuf entry packed 4B: src | (dst&127)<<24  (src < 2^17).
// ---------------------------------------------------------------------------
__global__ __launch_bounds__(256) void scatter_gemm1(
    const int* __restrict__ src, const int* __restrict__ dst,
    int* __restrict__ bcur, int* __restrict__ ebuf,
    const float* __restrict__ feat, const f16* __restrict__ W1t,
    f16* __restrict__ z1) {
    constexpr int PITCH = 136;
    __shared__ __align__(16) char smem[128 * PITCH * 2];  // 34816 B
    int tid = threadIdx.x;

    if (blockIdx.x < EBLOCKS) {
        int* h = (int*)smem;
        int* base_s = ((int*)smem) + 1024;
        for (int i = tid; i < NB; i += 256) h[i] = 0;
        __syncthreads();
        int base = blockIdx.x * 4096;
        int d[16], sv[16];
        for (int k = 0; k < 16; k++) {
            int e = base + k * 256 + tid;
            if (e < NEDGES) {
                d[k] = dst[e];
                sv[k] = src[e];
                atomicAdd(&h[d[k] >> BSHIFT], 1);
            } else {
                d[k] = -1;
            }
        }
        __syncthreads();
        for (int i = tid; i < NB; i += 256) {
            int c = h[i];
            if (c) base_s[i] = atomicAdd(&bcur[i], c);
            h[i] = 0;
        }
        __syncthreads();
        for (int k = 0; k < 16; k++) {
            if (d[k] >= 0) {
                int b = d[k] >> BSHIFT;
                int slot = atomicAdd(&h[b], 1);
                ebuf[base_s[b] + slot] = sv[k] | ((d[k] & 127) << 24);
            }
        }
        return;
    }

    // ---- GEMM-1 branch: z1 = f16(feat) @ W1t^T ----
    f16* wlds = (f16*)smem;
    for (int c = tid; c < 128 * 16; c += 256) {
        int n = c >> 4;
        int kc = c & 15;
        *(v8h*)&wlds[n * PITCH + kc * 8] = *(const v8h*)&W1t[n * 128 + kc * 8];
    }
    __syncthreads();

    int wave = tid >> 6, lane = tid & 63, quad = lane >> 4, l16 = lane & 15;
    int m0 = (blockIdx.x - EBLOCKS) * 64 + wave * 16;
    if (m0 >= NNODES) return;  // NNODES % 16 == 0

    v8h a[4];
    const float* arow = feat + (long)(m0 + l16) * 128 + quad * 8;
#pragma unroll
    for (int kb = 0; kb < 4; kb++) {
        float4 f0 = *(const float4*)(arow + kb * 32);
        float4 f1 = *(const float4*)(arow + kb * 32 + 4);
        v8h t = {(f16)f0.x, (f16)f0.y, (f16)f0.z, (f16)f0.w,
                 (f16)f1.x, (f16)f1.y, (f16)f1.z, (f16)f1.w};
        a[kb] = t;
    }

#pragma unroll
    for (int nt = 0; nt < 8; nt++) {
        v4f acc = {0.f, 0.f, 0.f, 0.f};
        const f16* brow = &wlds[(nt * 16 + l16) * PITCH + quad * 8];
#pragma unroll
        for (int kb = 0; kb < 4; kb++) {
            v8h b = *(const v8h*)(brow + kb * 32);
            acc = __builtin_amdgcn_mfma_f32_16x16x32_f16(a[kb], b, acc, 0, 0, 0);
        }
        int n = nt * 16 + l16;
#pragma unroll
        for (int r = 0; r < 4; r++)
            z1[(long)(m0 + quad * 4 + r) * 128 + n] = (f16)acc[r];
    }
}

// ---------------------------------------------------------------------------
// Per-bucket CSR fill (padded layout): count 128 nodes in LDS, scan, write
// begs/ends, place edges via LDS cursors. All writes in a ~10KB window.
// ---------------------------------------------------------------------------
__global__ __launch_bounds__(256) void fill_bucket(const int* __restrict__ ebuf,
                                                   const int* __restrict__ bcur,
                                                   int* __restrict__ begs,
                                                   int* __restrict__ ends,
                                                   int* __restrict__ csr) {
    __shared__ int lc[128];
    __shared__ int ls[256];
    int b = blockIdx.x;
    int tid = threadIdx.x;
    if (tid < 128) lc[tid] = 0;
    __syncthreads();
    int ebeg = b * CAP;
    int eend = bcur[b];  // = b*CAP + bucket count
    for (int e = ebeg + tid; e < eend; e += 256)
        atomicAdd(&lc[((unsigned)ebuf[e]) >> 24], 1);
    __syncthreads();
    int cnt = (tid < 128) ? lc[tid] : 0;
    ls[tid] = cnt;
    __syncthreads();
    for (int off = 1; off < 256; off <<= 1) {
        int t = (tid >= off) ? ls[tid - off] : 0;
        __syncthreads();
        ls[tid] += t;
        __syncthreads();
    }
    int excl = ls[tid] - cnt;
    int node = (b << BSHIFT) + tid;
    if (tid < 128 && node < NNODES) {
        begs[node] = ebeg + excl;
        ends[node] = ebeg + excl + cnt;
    }
    if (tid < 128) { ls[tid] = excl; lc[tid] = 0; }
    __syncthreads();
    for (int e = ebeg + tid; e < eend; e += 256) {
        int p = ebuf[e];
        int dloc = ((unsigned)p) >> 24;
        int slot = atomicAdd(&lc[dloc], 1);
        csr[ebeg + ls[dloc] + slot] = p & 0xFFFFFF;
    }
}

// ---------------------------------------------------------------------------
// Fused layer-1 gather + layer-2 projection, SUBGROUP-PER-NODE version.
// 1024-thread blocks = 16 waves = 64 nodes. Each 16-lane subgroup owns one
// node: 16 lanes x 16B = one full 256B z1 row per load, 8 edges in flight.
// Lane exclusively owns channels c*8..c*8+7 -> NO cross-lane reduction.
// Degree divergence handled by __any() wave-uniform loop + predication.
// h1 -> LDS atile[64], then ALL 16 waves run the 64x64 MFMA epilogue (4x4
// grid of 16x16 tiles). 4x node concurrency per wave vs round 2.
// ---------------------------------------------------------------------------
__global__ __launch_bounds__(1024, 8) void gather128_gemm2(
    const f16* __restrict__ z,        // z1, 256 B rows
    const int* __restrict__ begs, const int* __restrict__ ends,
    const int* __restrict__ csr,
    const float* __restrict__ b1,     // [128]
    const f16* __restrict__ W2t,      // [64,128]
    f16* __restrict__ z2)             // [NNODES,64]
{
    constexpr int PITCH = 136;
    __shared__ f16 w2lds[64 * PITCH];   // 17408 B
    __shared__ f16 atile[64 * PITCH];   // 17408 B
    int tid = threadIdx.x;

    // stage W2t (1024 threads, exactly 64*16 8-half chunks)
    {
        int n = tid >> 4, kc = tid & 15;
        *(v8h*)&w2lds[n * PITCH + kc * 8] = *(const v8h*)&W2t[n * 128 + kc * 8];
    }

    int wavei = tid >> 6;   // wave 0..15
    int lane = tid & 63;
    int sub = lane >> 4;    // subgroup 0..3 (one node each)
    int c = lane & 15;      // channel block: halves c*8 .. c*8+7
    int lnode = wavei * 4 + sub;             // 0..63
    int node = blockIdx.x * 64 + lnode;

    int beg = 0, end = 0;
    if (node < NNODES) { beg = begs[node]; end = ends[node]; }

    const char* zb = (const char*)z;
    unsigned coff = (unsigned)c << 4;   // byte offset of this lane's 16B chunk

    float af[8];
#pragma unroll
    for (int j = 0; j < 8; j++) af[j] = 0.f;

    // self row: all 64 lanes active (4 rows per instruction)
    if (node < NNODES) {
        v8h sv = *(const v8h*)(zb + ((unsigned)node << 8) + coff);
#pragma unroll
        for (int j = 0; j < 8; j++) af[j] = (float)sv[j];
    }

    int e = beg;
    while (__any(e < end)) {
        v8h u0 = {0,0,0,0,0,0,0,0}, u1 = {0,0,0,0,0,0,0,0};
        v8h u2 = {0,0,0,0,0,0,0,0}, u3 = {0,0,0,0,0,0,0,0};
        v8h u4 = {0,0,0,0,0,0,0,0}, u5 = {0,0,0,0,0,0,0,0};
        v8h u6 = {0,0,0,0,0,0,0,0}, u7 = {0,0,0,0,0,0,0,0};
        if (e     < end) u0 = *(const v8h*)(zb + (((unsigned)csr[e    ]) << 8) + coff);
        if (e + 1 < end) u1 = *(const v8h*)(zb + (((unsigned)csr[e + 1]) << 8) + coff);
        if (e + 2 < end) u2 = *(const v8h*)(zb + (((unsigned)csr[e + 2]) << 8) + coff);
        if (e + 3 < end) u3 = *(const v8h*)(zb + (((unsigned)csr[e + 3]) << 8) + coff);
        if (e + 4 < end) u4 = *(const v8h*)(zb + (((unsigned)csr[e + 4]) << 8) + coff);
        if (e + 5 < end) u5 = *(const v8h*)(zb + (((unsigned)csr[e + 5]) << 8) + coff);
        if (e + 6 < end) u6 = *(const v8h*)(zb + (((unsigned)csr[e + 6]) << 8) + coff);
        if (e + 7 < end) u7 = *(const v8h*)(zb + (((unsigned)csr[e + 7]) << 8) + coff);
        v8h s01 = u0 + u1, s23 = u2 + u3, s45 = u4 + u5, s67 = u6 + u7;
        v8h s03 = s01 + s23, s47 = s45 + s67;
        v8h s = s03 + s47;   // 8-edge f16 tree
#pragma unroll
        for (int j = 0; j < 8; j++) af[j] += (float)s[j];
        e += 8;
    }

    // normalize + bias + relu -> atile (no cross-lane reduce needed)
    {
        float inv = 1.0f / (float)(end - beg + 1);
        float4 bb0 = ((const float4*)b1)[c * 2];
        float4 bb1 = ((const float4*)b1)[c * 2 + 1];
        v8h o = {(f16)fmaxf(af[0] * inv + bb0.x, 0.f),
                 (f16)fmaxf(af[1] * inv + bb0.y, 0.f),
                 (f16)fmaxf(af[2] * inv + bb0.z, 0.f),
                 (f16)fmaxf(af[3] * inv + bb0.w, 0.f),
                 (f16)fmaxf(af[4] * inv + bb1.x, 0.f),
                 (f16)fmaxf(af[5] * inv + bb1.y, 0.f),
                 (f16)fmaxf(af[6] * inv + bb1.z, 0.f),
                 (f16)fmaxf(af[7] * inv + bb1.w, 0.f)};
        *(v8h*)&atile[lnode * PITCH + c * 8] = o;
    }
    __syncthreads();

    // ---- epilogue: z2[64 rows] = atile @ W2t^T; wave w -> tile (w>>2, w&3)
    {
        int wr = wavei >> 2, wc = wavei & 3;
        int quad = lane >> 4, l16 = lane & 15;
        const f16* arow = &atile[(wr * 16 + l16) * PITCH + quad * 8];
        const f16* brow = &w2lds[(wc * 16 + l16) * PITCH + quad * 8];
        v4f acc = {0.f, 0.f, 0.f, 0.f};
#pragma unroll
        for (int kb = 0; kb < 4; kb++) {
            v8h av = *(const v8h*)(arow + kb * 32);
            v8h bv = *(const v8h*)(brow + kb * 32);
            acc = __builtin_amdgcn_mfma_f32_16x16x32_f16(av, bv, acc, 0, 0, 0);
        }
        int n = wc * 16 + l16;
        int m0 = blockIdx.x * 64 + wr * 16;
#pragma unroll
        for (int r = 0; r < 4; r++) {
            int row = m0 + quad * 4 + r;
            if (row < NNODES) z2[(long)row * 64 + n] = (f16)acc[r];
        }
    }
}

// ---------------------------------------------------------------------------
// Layer-2 gather+normalize, SUBGROUP-PER-NODE: wave = 8x 8-lane subgroups,
// one node per subgroup (8 lanes x 16B = full 128B z2 row per load).
// 8 edges in flight per node, no cross-lane reduction, no tails.
// ---------------------------------------------------------------------------
__global__ __launch_bounds__(256, 8) void gather64(
    const f16* __restrict__ z, const int* __restrict__ begs,
    const int* __restrict__ ends, const int* __restrict__ csr,
    const float* __restrict__ bias, float4* __restrict__ out) {
    int tid = threadIdx.x;
    int lane = tid & 63;
    int c = lane & 7;                         // channel block
    int node = blockIdx.x * 32 + (tid >> 3);  // 3125*32 == NNODES exactly

    int beg = begs[node];
    int end = ends[node];

    const char* zb = (const char*)z;
    unsigned coff = (unsigned)c << 4;

    float af[8];
    {
        v8h sv = *(const v8h*)(zb + ((unsigned)node << 7) + coff);
#pragma unroll
        for (int j = 0; j < 8; j++) af[j] = (float)sv[j];
    }

    int e = beg;
    while (__any(e < end)) {
        v8h u0 = {0,0,0,0,0,0,0,0}, u1 = {0,0,0,0,0,0,0,0};
        v8h u2 = {0,0,0,0,0,0,0,0}, u3 = {0,0,0,0,0,0,0,0};
        v8h u4 = {0,0,0,0,0,0,0,0}, u5 = {0,0,0,0,0,0,0,0};
        v8h u6 = {0,0,0,0,0,0,0,0}, u7 = {0,0,0,0,0,0,0,0};
        if (e     < end) u0 = *(const v8h*)(zb + (((unsigned)csr[e    ]) << 7) + coff);
        if (e + 1 < end) u1 = *(const v8h*)(zb + (((unsigned)csr[e + 1]) << 7) + coff);
        if (e + 2 < end) u2 = *(const v8h*)(zb + (((unsigned)csr[e + 2]) << 7) + coff);
        if (e + 3 < end) u3 = *(const v8h*)(zb + (((unsigned)csr[e + 3]) << 7) + coff);
        if (e + 4 < end) u4 = *(const v8h*)(zb + (((unsigned)csr[e + 4]) << 7) + coff);
        if (e + 5 < end) u5 = *(const v8h*)(zb + (((unsigned)csr[e + 5]) << 7) + coff);
        if (e + 6 < end) u6 = *(const v8h*)(zb + (((unsigned)csr[e + 6]) << 7) + coff);
        if (e + 7 < end) u7 = *(const v8h*)(zb + (((unsigned)csr[e + 7]) << 7) + coff);
        v8h s01 = u0 + u1, s23 = u2 + u3, s45 = u4 + u5, s67 = u6 + u7;
        v8h s03 = s01 + s23, s47 = s45 + s67;
        v8h s = s03 + s47;
#pragma unroll
        for (int j = 0; j < 8; j++) af[j] += (float)s[j];
        e += 8;
    }

    {
        float inv = 1.0f / (float)(end - beg + 1);
        float4 b0 = ((const float4*)bias)[c * 2];
        float4 b1v = ((const float4*)bias)[c * 2 + 1];
        out[(long)node * 16 + c * 2] =
            make_float4(af[0] * inv + b0.x, af[1] * inv + b0.y,
                        af[2] * inv + b0.z, af[3] * inv + b0.w);
        out[(long)node * 16 + c * 2 + 1] =
            make_float4(af[4] * inv + b1v.x, af[5] * inv + b1v.y,
                        af[6] * inv + b1v.z, af[7] * inv + b1v.w);
    }
}

extern "C" void kernel_launch(void* const* d_in, const int* in_sizes, int n_in,
                              void* d_out, int out_size, void* d_ws, size_t ws_size,
                              hipStream_t stream) {
    const float* feat = (const float*)d_in[0];
    const float* W1   = (const float*)d_in[1];
    const float* b1   = (const float*)d_in[2];
    const float* W2   = (const float*)d_in[3];
    const float* b2   = (const float*)d_in[4];
    const int*   src  = (const int*)d_in[5];
    const int*   dst  = (const int*)d_in[6];
    float* out = (float*)d_out;

    // Workspace layout:
    //   bcur i32[782]       @ 0x0000000
    //   begs i32[100000]    @ 0x0001000  (400000 B)
    //   ends i32[100000]    @ 0x0063000  (400000 B)
    //   csr  i32[NB*CAP=2001920] @ 0x00C5000  (8.0 MB, bucket-padded)
    //   ebuf i32[NB*CAP]    @ 0x0870000  (8.0 MB, bucket-padded)
    //   z1   f16[12.8M]     @ 0x1100000  (25.6 MB)
    //   z2   f16[6.4M]      @ 0x2A00000  (12.8 MB)
    //   W1t  f16[16384]     @ 0x3700000
    //   W2t  f16[8192]      @ 0x3710000
    char* ws = (char*)d_ws;
    int* bcur = (int*)(ws + 0x0000000);
    int* begs = (int*)(ws + 0x0001000);
    int* ends = (int*)(ws + 0x0063000);
    int* csr  = (int*)(ws + 0x00C5000);
    int* ebuf = (int*)(ws + 0x0870000);
    f16* z1   = (f16*)(ws + 0x1100000);
    f16* z2   = (f16*)(ws + 0x2A00000);
    f16* W1t  = (f16*)(ws + 0x3700000);
    f16* W2t  = (f16*)(ws + 0x3710000);

    // 1. init cursors + weight prep (no memsets needed anywhere)
    init_k<<<100, 256, 0, stream>>>(bcur, W1, W1t, W2, W2t);

    // 2. edge scatter into padded buckets + layer-1 GEMM (fused)
    scatter_gemm1<<<EBLOCKS + GEMM_BLOCKS, 256, 0, stream>>>(src, dst, bcur, ebuf,
                                                             feat, W1t, z1);

    // 3. per-bucket CSR fill + per-node beg/end
    fill_bucket<<<NB, 256, 0, stream>>>(ebuf, bcur, begs, ends, csr);

    // 4. layer-1 gather (+bias+relu) fused with layer-2 projection
    //    64 nodes/block -> ceil(100000/64) = 1563 blocks
    gather128_gemm2<<<1563, 1024, 0, stream>>>(z1, begs, ends, csr, b1, W2t, z2);

    // 5. layer-2 gather (+bias) -> output; 32 nodes/block, 3125*32 = 100000
    gather64<<<3125, 256, 0, stream>>>(z2, begs, ends, csr, b2, (float4*)out);
}